// Round 1
// baseline (4015.934 us; speedup 1.0000x reference)
//
#include <hip/hip_runtime.h>

#define NN 4096
#define NE 65536
#define C 256
#define NL 3
#define NH 8
#define DH 32
#define EPS 1e-5f

// ---------------- lin1: h[n,c] = x[n]*w[c] + b[c] ----------------
__global__ __launch_bounds__(256) void lin1_kernel(const float* __restrict__ x,
        const float* __restrict__ w, const float* __restrict__ b,
        float* __restrict__ out) {
    int n = blockIdx.x, c = threadIdx.x;
    out[(size_t)n*C + c] = x[n]*w[c] + b[c];
}

// ---------------- scatter: agg[dst] += xin[src] ----------------
__global__ __launch_bounds__(256) void scatter_kernel(const float* __restrict__ xin,
        const int* __restrict__ ei, float* __restrict__ agg) {
    int e = blockIdx.x, c = threadIdx.x;
    int src = ei[e];
    int dst = ei[NE + e];
    atomicAdd(&agg[(size_t)dst*C + c], xin[(size_t)src*C + c]);
}

// ---------------- generic fp32 GEMM: out = relu?((A+A2) @ W^T + bias) + add1 + add2
// W is [Nout, K] row-major. M fixed = NN. Tiles 64x64x16, 256 thr, 4x4/thread.
__global__ __launch_bounds__(256) void gemm_kernel(const float* __restrict__ A,
        const float* __restrict__ A2, const float* __restrict__ W,
        const float* __restrict__ bias, const float* __restrict__ add1,
        const float* __restrict__ add2, float* __restrict__ out,
        int K, int Nout, int relu) {
    __shared__ float As[16][65];
    __shared__ float Ws[16][65];
    int bm = blockIdx.y * 64, bn = blockIdx.x * 64;
    int tid = threadIdx.x;
    int tx = tid & 15, ty = tid >> 4;   // compute layout
    int lk = tid & 15, ln = tid >> 4;   // load layout
    float acc[4][4] = {};
    for (int k0 = 0; k0 < K; k0 += 16) {
        __syncthreads();
        #pragma unroll
        for (int i = 0; i < 4; i++) {
            int m = ln + 16*i;
            float va = A[(size_t)(bm+m)*K + k0 + lk];
            if (A2) va += A2[(size_t)(bm+m)*K + k0 + lk];
            As[lk][m] = va;
            Ws[lk][m] = W[(size_t)(bn+m)*K + k0 + lk];
        }
        __syncthreads();
        #pragma unroll
        for (int k = 0; k < 16; k++) {
            float a[4], b[4];
            #pragma unroll
            for (int i = 0; i < 4; i++) a[i] = As[k][ty + 16*i];
            #pragma unroll
            for (int j = 0; j < 4; j++) b[j] = Ws[k][tx + 16*j];
            #pragma unroll
            for (int i = 0; i < 4; i++)
                #pragma unroll
                for (int j = 0; j < 4; j++)
                    acc[i][j] += a[i]*b[j];
        }
    }
    #pragma unroll
    for (int i = 0; i < 4; i++) {
        int m = bm + ty + 16*i;
        #pragma unroll
        for (int j = 0; j < 4; j++) {
            int n = bn + tx + 16*j;
            float v = acc[i][j] + bias[n];
            if (relu) v = fmaxf(v, 0.f);
            size_t idx = (size_t)m*Nout + n;
            if (add1) v += add1[idx];
            if (add2) v += add2[idx];
            out[idx] = v;
        }
    }
}

// ---------------- BatchNorm over node dim ----------------
__global__ __launch_bounds__(256) void bn_stats_kernel(const float* __restrict__ in,
        float* __restrict__ stats) {
    int c = threadIdx.x;
    int n0 = blockIdx.x * 64;
    float s = 0.f, s2 = 0.f;
    for (int i = 0; i < 64; i++) {
        float v = in[(size_t)(n0+i)*C + c];
        s += v; s2 += v*v;
    }
    atomicAdd(&stats[c], s);
    atomicAdd(&stats[C + c], s2);
}

__global__ __launch_bounds__(256) void bn_apply_kernel(const float* __restrict__ in,
        const float* __restrict__ stats, const float* __restrict__ g,
        const float* __restrict__ b, float* __restrict__ out) {
    int c = threadIdx.x;
    int n = blockIdx.x;
    float mean = stats[c] * (1.0f/NN);
    float var  = stats[C + c] * (1.0f/NN) - mean*mean;
    float sc = rsqrtf(var + EPS) * g[c];
    out[(size_t)n*C + c] = (in[(size_t)n*C + c] - mean) * sc + b[c];
}

// ---------------- flash attention fp32 ----------------
// grid (NN/64, NH), 256 threads. Thread (r=tid>>2, j=tid&3): query row r of the
// 64-query tile, key slice j (16 of 64 keys per tile). Online softmax per row;
// per-thread partial l/acc reduced across the 4 lanes of a group at the end.
__global__ __launch_bounds__(256) void attn_kernel(const float* __restrict__ q,
        const float* __restrict__ k, const float* __restrict__ v,
        float* __restrict__ o) {
    __shared__ float Ks[64*DH];
    __shared__ float Vs[64*DH];
    int tid = threadIdx.x;
    int r = tid >> 2, j = tid & 3;
    int qrow = blockIdx.x * 64 + r;
    int hb = blockIdx.y * DH;
    const float scale = 0.17677669529663687f;  // 1/sqrt(32)

    float qreg[DH];
    #pragma unroll
    for (int d4 = 0; d4 < DH/4; d4++) {
        float4 qv = *(const float4*)&q[(size_t)qrow*C + hb + d4*4];
        qreg[d4*4+0] = qv.x; qreg[d4*4+1] = qv.y;
        qreg[d4*4+2] = qv.z; qreg[d4*4+3] = qv.w;
    }
    float acc[DH];
    #pragma unroll
    for (int d = 0; d < DH; d++) acc[d] = 0.f;
    float m = -1e30f, l = 0.f;

    for (int kt = 0; kt < NN/64; kt++) {
        __syncthreads();
        #pragma unroll
        for (int i = 0; i < 2; i++) {
            int f = tid + i*256;          // 0..511 float4 slots
            int row = f >> 3, c4 = f & 7;
            ((float4*)Ks)[f] = *(const float4*)&k[(size_t)(kt*64+row)*C + hb + c4*4];
            ((float4*)Vs)[f] = *(const float4*)&v[(size_t)(kt*64+row)*C + hb + c4*4];
        }
        __syncthreads();

        float s[16];
        float tmax = -1e30f;
        #pragma unroll
        for (int kk = 0; kk < 16; kk++) {
            const float4* kr = (const float4*)&Ks[(j*16+kk)*DH];
            float dot = 0.f;
            #pragma unroll
            for (int d4 = 0; d4 < 8; d4++) {
                float4 kv = kr[d4];
                dot += qreg[d4*4+0]*kv.x + qreg[d4*4+1]*kv.y
                     + qreg[d4*4+2]*kv.z + qreg[d4*4+3]*kv.w;
            }
            s[kk] = dot * scale;
            tmax = fmaxf(tmax, s[kk]);
        }
        // row max across the 4 lanes of the group (adjacent lanes)
        tmax = fmaxf(tmax, __shfl_xor(tmax, 1));
        tmax = fmaxf(tmax, __shfl_xor(tmax, 2));
        float newm = fmaxf(m, tmax);
        float alpha = __expf(m - newm);
        float psum = 0.f;
        #pragma unroll
        for (int kk = 0; kk < 16; kk++) {
            s[kk] = __expf(s[kk] - newm);
            psum += s[kk];
        }
        l = l * alpha + psum;
        #pragma unroll
        for (int d = 0; d < DH; d++) acc[d] *= alpha;
        #pragma unroll
        for (int kk = 0; kk < 16; kk++) {
            float p = s[kk];
            const float4* vr = (const float4*)&Vs[(j*16+kk)*DH];
            #pragma unroll
            for (int d4 = 0; d4 < 8; d4++) {
                float4 vv = vr[d4];
                acc[d4*4+0] += p*vv.x; acc[d4*4+1] += p*vv.y;
                acc[d4*4+2] += p*vv.z; acc[d4*4+3] += p*vv.w;
            }
        }
        m = newm;
    }
    // reduce l and acc across the 4 lanes of the group
    float lt = l + __shfl_xor(l, 1);
    lt += __shfl_xor(lt, 2);
    float inv = 1.0f / lt;
    #pragma unroll
    for (int d = 0; d < DH; d++) {
        float a = acc[d] + __shfl_xor(acc[d], 1);
        a += __shfl_xor(a, 2);
        if ((d >> 3) == j)     // avoid runtime-indexed register array
            o[(size_t)qrow*C + hb + d] = a * inv;
    }
}

extern "C" void kernel_launch(void* const* d_in, const int* in_sizes, int n_in,
                              void* d_out, int out_size, void* d_ws, size_t ws_size,
                              hipStream_t stream) {
    const float* x      = (const float*)d_in[0];
    const int*   ei     = (const int*)d_in[1];
    const float* lin1_w = (const float*)d_in[2];
    const float* lin1_b = (const float*)d_in[3];
    const float* gin_w1 = (const float*)d_in[4];
    const float* gin_b1 = (const float*)d_in[5];
    const float* gin_w2 = (const float*)d_in[6];
    const float* gin_b2 = (const float*)d_in[7];
    const float* wq = (const float*)d_in[8];
    const float* wk = (const float*)d_in[9];
    const float* wv = (const float*)d_in[10];
    const float* wo = (const float*)d_in[11];
    const float* bq = (const float*)d_in[12];
    const float* bk = (const float*)d_in[13];
    const float* bv = (const float*)d_in[14];
    const float* bo = (const float*)d_in[15];
    const float* bn1_g = (const float*)d_in[16];
    const float* bn1_b = (const float*)d_in[17];
    const float* bn2_g = (const float*)d_in[18];
    const float* bn2_b = (const float*)d_in[19];
    const float* bn3_g = (const float*)d_in[20];
    const float* bn3_b = (const float*)d_in[21];
    const float* mw1 = (const float*)d_in[22];
    const float* mb1 = (const float*)d_in[23];
    const float* mw2 = (const float*)d_in[24];
    const float* mb2 = (const float*)d_in[25];

    const size_t NC = (size_t)NN * C;
    float* bufA = (float*)d_ws;      // xin / h
    float* bufB = bufA + NC;
    float* bufC = bufB + NC;
    float* bufD = bufC + NC;
    float* bufE = bufD + NC;         // h1
    float* bufF = bufE + NC;         // o / h2
    float* bufG = bufF + NC;         // mlp hidden [NN, 2C]
    float* stats = bufG + 2*NC;      // 2*C accumulators

    dim3 blk(256);
    dim3 gemmCC(C/64, NN/64);        // Nout=256
    dim3 gemmC2(2*C/64, NN/64);      // Nout=512

    lin1_kernel<<<NN, blk, 0, stream>>>(x, lin1_w, lin1_b, bufA);

    for (int l = 0; l < NL; l++) {
        const float* gw1 = gin_w1 + (size_t)l*C*C;
        const float* gb1 = gin_b1 + (size_t)l*C;
        const float* gw2 = gin_w2 + (size_t)l*C*C;
        const float* gb2 = gin_b2 + (size_t)l*C;
        const float* lwq = wq + (size_t)l*C*C; const float* lbq = bq + (size_t)l*C;
        const float* lwk = wk + (size_t)l*C*C; const float* lbk = bk + (size_t)l*C;
        const float* lwv = wv + (size_t)l*C*C; const float* lbv = bv + (size_t)l*C;
        const float* lwo = wo + (size_t)l*C*C; const float* lbo = bo + (size_t)l*C;
        const float* lmw1 = mw1 + (size_t)l*2*C*C; const float* lmb1 = mb1 + (size_t)l*2*C;
        const float* lmw2 = mw2 + (size_t)l*2*C*C; const float* lmb2 = mb2 + (size_t)l*C;

        // ---- GIN branch ----
        hipMemsetAsync(bufB, 0, NC*sizeof(float), stream);
        scatter_kernel<<<NE, blk, 0, stream>>>(bufA, ei, bufB);
        // t1 = relu((xin+agg) @ gw1^T + gb1)
        gemm_kernel<<<gemmCC, blk, 0, stream>>>(bufA, bufB, gw1, gb1, nullptr, nullptr, bufC, C, C, 1);
        // pre1 = t1 @ gw2^T + gb2 + xin
        gemm_kernel<<<gemmCC, blk, 0, stream>>>(bufC, nullptr, gw2, gb2, bufA, nullptr, bufD, C, C, 0);
        hipMemsetAsync(stats, 0, 2*C*sizeof(float), stream);
        bn_stats_kernel<<<NN/64, blk, 0, stream>>>(bufD, stats);
        bn_apply_kernel<<<NN, blk, 0, stream>>>(bufD, stats, bn1_g + (size_t)l*C, bn1_b + (size_t)l*C, bufE);

        // ---- attention branch ----
        gemm_kernel<<<gemmCC, blk, 0, stream>>>(bufA, nullptr, lwq, lbq, nullptr, nullptr, bufB, C, C, 0);
        gemm_kernel<<<gemmCC, blk, 0, stream>>>(bufA, nullptr, lwk, lbk, nullptr, nullptr, bufC, C, C, 0);
        gemm_kernel<<<gemmCC, blk, 0, stream>>>(bufA, nullptr, lwv, lbv, nullptr, nullptr, bufD, C, C, 0);
        attn_kernel<<<dim3(NN/64, NH), blk, 0, stream>>>(bufB, bufC, bufD, bufF);
        // pre2 = o @ wo^T + bo + xin
        gemm_kernel<<<gemmCC, blk, 0, stream>>>(bufF, nullptr, lwo, lbo, bufA, nullptr, bufB, C, C, 0);
        hipMemsetAsync(stats, 0, 2*C*sizeof(float), stream);
        bn_stats_kernel<<<NN/64, blk, 0, stream>>>(bufB, stats);
        bn_apply_kernel<<<NN, blk, 0, stream>>>(bufB, stats, bn2_g + (size_t)l*C, bn2_b + (size_t)l*C, bufF);

        // ---- feedforward: s = h1+h2 fused as input addend ----
        gemm_kernel<<<gemmC2, blk, 0, stream>>>(bufE, bufF, lmw1, lmb1, nullptr, nullptr, bufG, C, 2*C, 1);
        // pre3 = hid @ mw2^T + mb2 + h1 + h2
        gemm_kernel<<<gemmCC, blk, 0, stream>>>(bufG, nullptr, lmw2, lmb2, bufE, bufF, bufB, 2*C, C, 0);
        hipMemsetAsync(stats, 0, 2*C*sizeof(float), stream);
        bn_stats_kernel<<<NN/64, blk, 0, stream>>>(bufB, stats);
        float* hout = (l == NL-1) ? (float*)d_out : bufA;
        bn_apply_kernel<<<NN, blk, 0, stream>>>(bufB, stats, bn3_g + (size_t)l*C, bn3_b + (size_t)l*C, hout);
    }
}

// Round 2
// 1698.131 us; speedup vs baseline: 2.3649x; 2.3649x over previous
//
#include <hip/hip_runtime.h>

#define NN 4096
#define NE 65536
#define C 256
#define NL 3
#define NH 8
#define DH 32
#define EPS 1e-5f

typedef __bf16 bf16x8 __attribute__((ext_vector_type(8)));
typedef float f32x4 __attribute__((ext_vector_type(4)));

// ---------------- lin1: h[n,c] = x[n]*w[c] + b[c] ----------------
__global__ __launch_bounds__(256) void lin1_kernel(const float* __restrict__ x,
        const float* __restrict__ w, const float* __restrict__ b,
        float* __restrict__ out) {
    int n = blockIdx.x, c = threadIdx.x;
    out[(size_t)n*C + c] = x[n]*w[c] + b[c];
}

// ---------------- scatter: agg[dst] += xin[src] ----------------
__global__ __launch_bounds__(256) void scatter_kernel(const float* __restrict__ xin,
        const int* __restrict__ ei, float* __restrict__ agg) {
    int e = blockIdx.x, c = threadIdx.x;
    int src = ei[e];
    int dst = ei[NE + e];
    atomicAdd(&agg[(size_t)dst*C + c], xin[(size_t)src*C + c]);
}

// ---------------- generic fp32 GEMM: out = relu?((A+A2) @ W^T + bias) + add1 + add2
__global__ __launch_bounds__(256) void gemm_kernel(const float* __restrict__ A,
        const float* __restrict__ A2, const float* __restrict__ W,
        const float* __restrict__ bias, const float* __restrict__ add1,
        const float* __restrict__ add2, float* __restrict__ out,
        int K, int Nout, int relu) {
    __shared__ float As[16][65];
    __shared__ float Ws[16][65];
    int bm = blockIdx.y * 64, bn = blockIdx.x * 64;
    int tid = threadIdx.x;
    int tx = tid & 15, ty = tid >> 4;
    int lk = tid & 15, ln = tid >> 4;
    float acc[4][4] = {};
    for (int k0 = 0; k0 < K; k0 += 16) {
        __syncthreads();
        #pragma unroll
        for (int i = 0; i < 4; i++) {
            int m = ln + 16*i;
            float va = A[(size_t)(bm+m)*K + k0 + lk];
            if (A2) va += A2[(size_t)(bm+m)*K + k0 + lk];
            As[lk][m] = va;
            Ws[lk][m] = W[(size_t)(bn+m)*K + k0 + lk];
        }
        __syncthreads();
        #pragma unroll
        for (int k = 0; k < 16; k++) {
            float a[4], b[4];
            #pragma unroll
            for (int i = 0; i < 4; i++) a[i] = As[k][ty + 16*i];
            #pragma unroll
            for (int j = 0; j < 4; j++) b[j] = Ws[k][tx + 16*j];
            #pragma unroll
            for (int i = 0; i < 4; i++)
                #pragma unroll
                for (int j = 0; j < 4; j++)
                    acc[i][j] += a[i]*b[j];
        }
    }
    #pragma unroll
    for (int i = 0; i < 4; i++) {
        int m = bm + ty + 16*i;
        #pragma unroll
        for (int j = 0; j < 4; j++) {
            int n = bn + tx + 16*j;
            float v = acc[i][j] + bias[n];
            if (relu) v = fmaxf(v, 0.f);
            size_t idx = (size_t)m*Nout + n;
            if (add1) v += add1[idx];
            if (add2) v += add2[idx];
            out[idx] = v;
        }
    }
}

// ---------------- BatchNorm over node dim ----------------
__global__ __launch_bounds__(256) void bn_stats_kernel(const float* __restrict__ in,
        float* __restrict__ stats) {
    int c = threadIdx.x;
    int n0 = blockIdx.x * 64;
    float s = 0.f, s2 = 0.f;
    for (int i = 0; i < 64; i++) {
        float v = in[(size_t)(n0+i)*C + c];
        s += v; s2 += v*v;
    }
    atomicAdd(&stats[c], s);
    atomicAdd(&stats[C + c], s2);
}

__global__ __launch_bounds__(256) void bn_apply_kernel(const float* __restrict__ in,
        const float* __restrict__ stats, const float* __restrict__ g,
        const float* __restrict__ b, float* __restrict__ out) {
    int c = threadIdx.x;
    int n = blockIdx.x;
    float mean = stats[c] * (1.0f/NN);
    float var  = stats[C + c] * (1.0f/NN) - mean*mean;
    float sc = rsqrtf(var + EPS) * g[c];
    out[(size_t)n*C + c] = (in[(size_t)n*C + c] - mean) * sc + b[c];
}

// ---------------- bf16 MFMA flash attention ----------------
// grid (NN/64, NH), 256 thr = 4 waves. Wave w owns q-rows qb+w*16..+15.
// Per K-tile of 64 keys: stage K[64][32] row-major bf16 + V^T[32][64+pad] bf16,
// QK^T via 4x mfma_16x16x32_bf16 (A=Q frag, B=K rows), online softmax on the
// C-layout S (rows quad*4+r, col lane&15; row-reduce = shfl_xor 1/2/4/8 within
// the 16-lane quad group), P (bf16) round-trips wave-private LDS to A-layout,
// PV via 4x mfma accumulating O in C-layout f32.
#define ATT_PAD 72
__global__ __launch_bounds__(256) void attn_kernel(const float* __restrict__ q,
        const float* __restrict__ k, const float* __restrict__ v,
        float* __restrict__ o) {
    __shared__ __bf16 Ks[64*32];            // [key][dh]
    __shared__ __bf16 Vst[32*ATT_PAD];      // [dh][key], pad 72 breaks conflicts
    __shared__ __bf16 Pb[4][16*ATT_PAD];    // per-wave P [q][key]
    int tid = threadIdx.x;
    int wave = tid >> 6, lane = tid & 63;
    int ln = lane & 15, quad = lane >> 4;
    int hb = blockIdx.y * DH;
    int qb = blockIdx.x * 64;
    const float scale = 0.17677669529663687f;  // 1/sqrt(32)

    // Q fragment (A-layout: m=ln, k=quad*8+j), scale folded into bf16 cvt
    bf16x8 qf;
    {
        const float* qp = &q[(size_t)(qb + wave*16 + ln)*C + hb + quad*8];
        #pragma unroll
        for (int j = 0; j < 8; j++) qf[j] = (__bf16)(qp[j] * scale);
    }
    f32x4 o0 = {0.f,0.f,0.f,0.f}, o1 = {0.f,0.f,0.f,0.f};
    float m_[4], l_[4];
    #pragma unroll
    for (int r = 0; r < 4; r++) { m_[r] = -1e30f; l_[r] = 0.f; }

    int srow = tid & 63, sg = tid >> 6;  // staging: key row, dh-group
    for (int kt = 0; kt < NN/64; kt++) {
        int kb = kt*64;
        __syncthreads();
        {
            const float* kp = &k[(size_t)(kb+srow)*C + hb + sg*8];
            bf16x8 tmp;
            #pragma unroll
            for (int j = 0; j < 8; j++) tmp[j] = (__bf16)kp[j];
            *(bf16x8*)&Ks[srow*32 + sg*8] = tmp;
            const float* vp = &v[(size_t)(kb+srow)*C + hb + sg*8];
            #pragma unroll
            for (int j = 0; j < 8; j++) Vst[(sg*8+j)*ATT_PAD + srow] = (__bf16)vp[j];
        }
        __syncthreads();
        // QK^T -> S[16q][64key] in C-layout across 4 subtiles
        f32x4 s[4];
        #pragma unroll
        for (int sub = 0; sub < 4; sub++) {
            bf16x8 bf = *(const bf16x8*)&Ks[(sub*16+ln)*32 + quad*8];
            f32x4 z = {0.f,0.f,0.f,0.f};
            s[sub] = __builtin_amdgcn_mfma_f32_16x16x32_bf16(qf, bf, z, 0, 0, 0);
        }
        // online softmax (rows quad*4+r)
        float tm[4];
        #pragma unroll
        for (int r = 0; r < 4; r++)
            tm[r] = fmaxf(fmaxf(s[0][r], s[1][r]), fmaxf(s[2][r], s[3][r]));
        #pragma unroll
        for (int mask = 1; mask <= 8; mask <<= 1)
            #pragma unroll
            for (int r = 0; r < 4; r++)
                tm[r] = fmaxf(tm[r], __shfl_xor(tm[r], mask));
        float al[4], ps[4];
        #pragma unroll
        for (int r = 0; r < 4; r++) {
            float nm = fmaxf(m_[r], tm[r]);
            al[r] = __expf(m_[r] - nm);
            m_[r] = nm;
            ps[r] = 0.f;
        }
        #pragma unroll
        for (int sub = 0; sub < 4; sub++)
            #pragma unroll
            for (int r = 0; r < 4; r++) {
                float p = __expf(s[sub][r] - m_[r]);
                s[sub][r] = p;
                ps[r] += p;
            }
        #pragma unroll
        for (int mask = 1; mask <= 8; mask <<= 1)
            #pragma unroll
            for (int r = 0; r < 4; r++)
                ps[r] += __shfl_xor(ps[r], mask);
        #pragma unroll
        for (int r = 0; r < 4; r++)
            l_[r] = l_[r]*al[r] + ps[r];
        #pragma unroll
        for (int r = 0; r < 4; r++) { o0[r] *= al[r]; o1[r] *= al[r]; }
        // P -> wave-private LDS (C-layout write), read back in A-layout.
        // Same-wave DS ops are ordered; no barrier needed.
        __bf16* pw = Pb[wave];
        #pragma unroll
        for (int sub = 0; sub < 4; sub++)
            #pragma unroll
            for (int r = 0; r < 4; r++)
                pw[(quad*4+r)*ATT_PAD + sub*16 + ln] = (__bf16)s[sub][r];
        #pragma unroll
        for (int kt2 = 0; kt2 < 2; kt2++) {
            bf16x8 pa = *(const bf16x8*)&pw[ln*ATT_PAD + kt2*32 + quad*8];
            bf16x8 b0 = *(const bf16x8*)&Vst[ln*ATT_PAD + kt2*32 + quad*8];
            bf16x8 b1 = *(const bf16x8*)&Vst[(16+ln)*ATT_PAD + kt2*32 + quad*8];
            o0 = __builtin_amdgcn_mfma_f32_16x16x32_bf16(pa, b0, o0, 0, 0, 0);
            o1 = __builtin_amdgcn_mfma_f32_16x16x32_bf16(pa, b1, o1, 0, 0, 0);
        }
    }
    #pragma unroll
    for (int r = 0; r < 4; r++) {
        float inv = 1.0f / l_[r];
        int row = qb + wave*16 + quad*4 + r;
        o[(size_t)row*C + hb + ln]      = o0[r] * inv;
        o[(size_t)row*C + hb + 16 + ln] = o1[r] * inv;
    }
}

extern "C" void kernel_launch(void* const* d_in, const int* in_sizes, int n_in,
                              void* d_out, int out_size, void* d_ws, size_t ws_size,
                              hipStream_t stream) {
    const float* x      = (const float*)d_in[0];
    const int*   ei     = (const int*)d_in[1];
    const float* lin1_w = (const float*)d_in[2];
    const float* lin1_b = (const float*)d_in[3];
    const float* gin_w1 = (const float*)d_in[4];
    const float* gin_b1 = (const float*)d_in[5];
    const float* gin_w2 = (const float*)d_in[6];
    const float* gin_b2 = (const float*)d_in[7];
    const float* wq = (const float*)d_in[8];
    const float* wk = (const float*)d_in[9];
    const float* wv = (const float*)d_in[10];
    const float* wo = (const float*)d_in[11];
    const float* bq = (const float*)d_in[12];
    const float* bk = (const float*)d_in[13];
    const float* bv = (const float*)d_in[14];
    const float* bo = (const float*)d_in[15];
    const float* bn1_g = (const float*)d_in[16];
    const float* bn1_b = (const float*)d_in[17];
    const float* bn2_g = (const float*)d_in[18];
    const float* bn2_b = (const float*)d_in[19];
    const float* bn3_g = (const float*)d_in[20];
    const float* bn3_b = (const float*)d_in[21];
    const float* mw1 = (const float*)d_in[22];
    const float* mb1 = (const float*)d_in[23];
    const float* mw2 = (const float*)d_in[24];
    const float* mb2 = (const float*)d_in[25];

    const size_t NC = (size_t)NN * C;
    float* bufA = (float*)d_ws;      // xin / h
    float* bufB = bufA + NC;
    float* bufC = bufB + NC;
    float* bufD = bufC + NC;
    float* bufE = bufD + NC;         // h1
    float* bufF = bufE + NC;         // o / h2
    float* bufG = bufF + NC;         // mlp hidden [NN, 2C]
    float* stats = bufG + 2*NC;      // 2*C accumulators

    dim3 blk(256);
    dim3 gemmCC(C/64, NN/64);        // Nout=256
    dim3 gemmC2(2*C/64, NN/64);      // Nout=512

    lin1_kernel<<<NN, blk, 0, stream>>>(x, lin1_w, lin1_b, bufA);

    for (int l = 0; l < NL; l++) {
        const float* gw1 = gin_w1 + (size_t)l*C*C;
        const float* gb1 = gin_b1 + (size_t)l*C;
        const float* gw2 = gin_w2 + (size_t)l*C*C;
        const float* gb2 = gin_b2 + (size_t)l*C;
        const float* lwq = wq + (size_t)l*C*C; const float* lbq = bq + (size_t)l*C;
        const float* lwk = wk + (size_t)l*C*C; const float* lbk = bk + (size_t)l*C;
        const float* lwv = wv + (size_t)l*C*C; const float* lbv = bv + (size_t)l*C;
        const float* lwo = wo + (size_t)l*C*C; const float* lbo = bo + (size_t)l*C;
        const float* lmw1 = mw1 + (size_t)l*2*C*C; const float* lmb1 = mb1 + (size_t)l*2*C;
        const float* lmw2 = mw2 + (size_t)l*2*C*C; const float* lmb2 = mb2 + (size_t)l*C;

        // ---- GIN branch ----
        hipMemsetAsync(bufB, 0, NC*sizeof(float), stream);
        scatter_kernel<<<NE, blk, 0, stream>>>(bufA, ei, bufB);
        gemm_kernel<<<gemmCC, blk, 0, stream>>>(bufA, bufB, gw1, gb1, nullptr, nullptr, bufC, C, C, 1);
        gemm_kernel<<<gemmCC, blk, 0, stream>>>(bufC, nullptr, gw2, gb2, bufA, nullptr, bufD, C, C, 0);
        hipMemsetAsync(stats, 0, 2*C*sizeof(float), stream);
        bn_stats_kernel<<<NN/64, blk, 0, stream>>>(bufD, stats);
        bn_apply_kernel<<<NN, blk, 0, stream>>>(bufD, stats, bn1_g + (size_t)l*C, bn1_b + (size_t)l*C, bufE);

        // ---- attention branch ----
        gemm_kernel<<<gemmCC, blk, 0, stream>>>(bufA, nullptr, lwq, lbq, nullptr, nullptr, bufB, C, C, 0);
        gemm_kernel<<<gemmCC, blk, 0, stream>>>(bufA, nullptr, lwk, lbk, nullptr, nullptr, bufC, C, C, 0);
        gemm_kernel<<<gemmCC, blk, 0, stream>>>(bufA, nullptr, lwv, lbv, nullptr, nullptr, bufD, C, C, 0);
        attn_kernel<<<dim3(NN/64, NH), blk, 0, stream>>>(bufB, bufC, bufD, bufF);
        gemm_kernel<<<gemmCC, blk, 0, stream>>>(bufF, nullptr, lwo, lbo, bufA, nullptr, bufB, C, C, 0);
        hipMemsetAsync(stats, 0, 2*C*sizeof(float), stream);
        bn_stats_kernel<<<NN/64, blk, 0, stream>>>(bufB, stats);
        bn_apply_kernel<<<NN, blk, 0, stream>>>(bufB, stats, bn2_g + (size_t)l*C, bn2_b + (size_t)l*C, bufF);

        // ---- feedforward ----
        gemm_kernel<<<gemmC2, blk, 0, stream>>>(bufE, bufF, lmw1, lmb1, nullptr, nullptr, bufG, C, 2*C, 1);
        gemm_kernel<<<gemmCC, blk, 0, stream>>>(bufG, nullptr, lmw2, lmb2, bufE, bufF, bufB, 2*C, C, 0);
        hipMemsetAsync(stats, 0, 2*C*sizeof(float), stream);
        bn_stats_kernel<<<NN/64, blk, 0, stream>>>(bufB, stats);
        float* hout = (l == NL-1) ? (float*)d_out : bufA;
        bn_apply_kernel<<<NN, blk, 0, stream>>>(bufB, stats, bn3_g + (size_t)l*C, bn3_b + (size_t)l*C, hout);
    }
}

// Round 3
// 987.838 us; speedup vs baseline: 4.0654x; 1.7190x over previous
//
#include <hip/hip_runtime.h>

#define NN 4096
#define NE 65536
#define C 256
#define NL 3
#define NH 8
#define DH 32
#define EPS 1e-5f

typedef __bf16 bf16x8 __attribute__((ext_vector_type(8)));
typedef float f32x4 __attribute__((ext_vector_type(4)));

// scale * log2(e), folded into Q at projection time so softmax uses exp2
#define QSCALE (0.17677669529663687f * 1.4426950408889634f)

// ---------------- lin1: h[n,c] = x[n]*w[c] + b[c] ----------------
__global__ __launch_bounds__(256) void lin1_kernel(const float* __restrict__ x,
        const float* __restrict__ w, const float* __restrict__ b,
        float* __restrict__ out) {
    int n = blockIdx.x, c = threadIdx.x;
    out[(size_t)n*C + c] = x[n]*w[c] + b[c];
}

// ---------------- scatter: agg[dst] += xin[src] ----------------
__global__ __launch_bounds__(256) void scatter_kernel(const float* __restrict__ xin,
        const int* __restrict__ ei, float* __restrict__ agg) {
    int e = blockIdx.x, c = threadIdx.x;
    int src = ei[e];
    int dst = ei[NE + e];
    atomicAdd(&agg[(size_t)dst*C + c], xin[(size_t)src*C + c]);
}

// ---------------- bf16 MFMA GEMM ----------------
// out[M,Nout] = relu?((A+A2) @ W^T + bias) + add1 + add2, fp32 in/out,
// bf16 MFMA inner. Optionally accumulates BN partial stats (sum, sumsq per
// col) via atomics. Tile 64x64, BK=64, 256 thr = 4 waves (wave = 16-col strip).
#define GS 72   // LDS row stride in bf16 (144B = 36 banks -> 2-way, free)
__global__ __launch_bounds__(256) void gemm_bf16(const float* __restrict__ A,
        const float* __restrict__ A2, const float* __restrict__ W,
        const float* __restrict__ bias, const float* __restrict__ add1,
        const float* __restrict__ add2, float* __restrict__ out,
        float* __restrict__ stats, int K, int Nout, int relu) {
    __shared__ __bf16 As[64*GS];
    __shared__ __bf16 Ws[64*GS];
    int tid = threadIdx.x;
    int wave = tid >> 6, lane = tid & 63;
    int ln = lane & 15, quad = lane >> 4;
    int bm = blockIdx.y * 64, bn = blockIdx.x * 64;
    int row = tid >> 2, kseg = (tid & 3) * 16;
    f32x4 acc[4] = {};
    for (int k0 = 0; k0 < K; k0 += 64) {
        __syncthreads();
        {
            const float* ap = &A[(size_t)(bm+row)*K + k0 + kseg];
            __bf16 bt[16];
            if (A2) {
                const float* ap2 = &A2[(size_t)(bm+row)*K + k0 + kseg];
                #pragma unroll
                for (int i = 0; i < 4; i++) {
                    float4 t = *(const float4*)(ap + i*4);
                    float4 t2 = *(const float4*)(ap2 + i*4);
                    bt[i*4+0] = (__bf16)(t.x+t2.x); bt[i*4+1] = (__bf16)(t.y+t2.y);
                    bt[i*4+2] = (__bf16)(t.z+t2.z); bt[i*4+3] = (__bf16)(t.w+t2.w);
                }
            } else {
                #pragma unroll
                for (int i = 0; i < 4; i++) {
                    float4 t = *(const float4*)(ap + i*4);
                    bt[i*4+0] = (__bf16)t.x; bt[i*4+1] = (__bf16)t.y;
                    bt[i*4+2] = (__bf16)t.z; bt[i*4+3] = (__bf16)t.w;
                }
            }
            *(bf16x8*)&As[row*GS + kseg]     = *(bf16x8*)&bt[0];
            *(bf16x8*)&As[row*GS + kseg + 8] = *(bf16x8*)&bt[8];
            const float* wp = &W[(size_t)(bn+row)*K + k0 + kseg];
            #pragma unroll
            for (int i = 0; i < 4; i++) {
                float4 t = *(const float4*)(wp + i*4);
                bt[i*4+0] = (__bf16)t.x; bt[i*4+1] = (__bf16)t.y;
                bt[i*4+2] = (__bf16)t.z; bt[i*4+3] = (__bf16)t.w;
            }
            *(bf16x8*)&Ws[row*GS + kseg]     = *(bf16x8*)&bt[0];
            *(bf16x8*)&Ws[row*GS + kseg + 8] = *(bf16x8*)&bt[8];
        }
        __syncthreads();
        #pragma unroll
        for (int kt2 = 0; kt2 < 2; kt2++) {
            bf16x8 bfr = *(const bf16x8*)&Ws[(wave*16+ln)*GS + kt2*32 + quad*8];
            #pragma unroll
            for (int i = 0; i < 4; i++) {
                bf16x8 afr = *(const bf16x8*)&As[(i*16+ln)*GS + kt2*32 + quad*8];
                acc[i] = __builtin_amdgcn_mfma_f32_16x16x32_bf16(afr, bfr, acc[i], 0, 0, 0);
            }
        }
    }
    int col = bn + wave*16 + ln;
    float bsv = bias[col];
    float ssum = 0.f, ssq = 0.f;
    #pragma unroll
    for (int i = 0; i < 4; i++) {
        #pragma unroll
        for (int r = 0; r < 4; r++) {
            int rw = bm + i*16 + quad*4 + r;
            float vv = acc[i][r] + bsv;
            if (relu) vv = fmaxf(vv, 0.f);
            size_t idx = (size_t)rw*Nout + col;
            if (add1) vv += add1[idx];
            if (add2) vv += add2[idx];
            out[idx] = vv;
            ssum += vv; ssq += vv*vv;
        }
    }
    if (stats) {
        ssum += __shfl_xor(ssum, 16); ssum += __shfl_xor(ssum, 32);
        ssq  += __shfl_xor(ssq, 16);  ssq  += __shfl_xor(ssq, 32);
        if (quad == 0) {
            atomicAdd(&stats[col], ssum);
            atomicAdd(&stats[Nout + col], ssq);
        }
    }
}

// ---------------- fused QKV projection, bf16 outputs ----------------
// grid (4, 64, 3): z selects Q/K/V. Q pre-scaled by QSCALE.
__global__ __launch_bounds__(256) void qkv_gemm(const float* __restrict__ A,
        const float* __restrict__ wq, const float* __restrict__ wk,
        const float* __restrict__ wv, const float* __restrict__ bq,
        const float* __restrict__ bk, const float* __restrict__ bv,
        __bf16* __restrict__ qo, __bf16* __restrict__ ko,
        __bf16* __restrict__ vo) {
    int z = blockIdx.z;
    const float* W    = z == 0 ? wq : (z == 1 ? wk : wv);
    const float* bias = z == 0 ? bq : (z == 1 ? bk : bv);
    __bf16* out       = z == 0 ? qo : (z == 1 ? ko : vo);
    float oscale      = z == 0 ? QSCALE : 1.0f;
    __shared__ __bf16 As[64*GS];
    __shared__ __bf16 Ws[64*GS];
    int tid = threadIdx.x;
    int wave = tid >> 6, lane = tid & 63;
    int ln = lane & 15, quad = lane >> 4;
    int bm = blockIdx.y * 64, bn = blockIdx.x * 64;
    int row = tid >> 2, kseg = (tid & 3) * 16;
    f32x4 acc[4] = {};
    for (int k0 = 0; k0 < C; k0 += 64) {
        __syncthreads();
        {
            __bf16 bt[16];
            const float* ap = &A[(size_t)(bm+row)*C + k0 + kseg];
            #pragma unroll
            for (int i = 0; i < 4; i++) {
                float4 t = *(const float4*)(ap + i*4);
                bt[i*4+0] = (__bf16)t.x; bt[i*4+1] = (__bf16)t.y;
                bt[i*4+2] = (__bf16)t.z; bt[i*4+3] = (__bf16)t.w;
            }
            *(bf16x8*)&As[row*GS + kseg]     = *(bf16x8*)&bt[0];
            *(bf16x8*)&As[row*GS + kseg + 8] = *(bf16x8*)&bt[8];
            const float* wp = &W[(size_t)(bn+row)*C + k0 + kseg];
            #pragma unroll
            for (int i = 0; i < 4; i++) {
                float4 t = *(const float4*)(wp + i*4);
                bt[i*4+0] = (__bf16)t.x; bt[i*4+1] = (__bf16)t.y;
                bt[i*4+2] = (__bf16)t.z; bt[i*4+3] = (__bf16)t.w;
            }
            *(bf16x8*)&Ws[row*GS + kseg]     = *(bf16x8*)&bt[0];
            *(bf16x8*)&Ws[row*GS + kseg + 8] = *(bf16x8*)&bt[8];
        }
        __syncthreads();
        #pragma unroll
        for (int kt2 = 0; kt2 < 2; kt2++) {
            bf16x8 bfr = *(const bf16x8*)&Ws[(wave*16+ln)*GS + kt2*32 + quad*8];
            #pragma unroll
            for (int i = 0; i < 4; i++) {
                bf16x8 afr = *(const bf16x8*)&As[(i*16+ln)*GS + kt2*32 + quad*8];
                acc[i] = __builtin_amdgcn_mfma_f32_16x16x32_bf16(afr, bfr, acc[i], 0, 0, 0);
            }
        }
    }
    int col = bn + wave*16 + ln;
    float bsv = bias[col];
    #pragma unroll
    for (int i = 0; i < 4; i++)
        #pragma unroll
        for (int r = 0; r < 4; r++) {
            int rw = bm + i*16 + quad*4 + r;
            out[(size_t)rw*C + col] = (__bf16)((acc[i][r] + bsv) * oscale);
        }
}

// ---------------- BatchNorm apply ----------------
__global__ __launch_bounds__(256) void bn_apply_kernel(const float* __restrict__ in,
        const float* __restrict__ stats, const float* __restrict__ g,
        const float* __restrict__ b, float* __restrict__ out) {
    int c = threadIdx.x;
    int n = blockIdx.x;
    float mean = stats[c] * (1.0f/NN);
    float var  = stats[C + c] * (1.0f/NN) - mean*mean;
    float sc = rsqrtf(var + EPS) * g[c];
    out[(size_t)n*C + c] = (in[(size_t)n*C + c] - mean) * sc + b[c];
}

// ---------------- bf16 MFMA flash attention, 128 queries/block ----------------
// grid (NN/128, NH), 256 thr = 4 waves; wave owns 32 q-rows (2 A-frags).
// Q pre-scaled by scale*log2e -> softmax in exp2 domain.
#define ATT_PAD 72
__global__ __launch_bounds__(256) void attn_kernel(const __bf16* __restrict__ q,
        const __bf16* __restrict__ k, const __bf16* __restrict__ v,
        float* __restrict__ o) {
    __shared__ __bf16 Ks[64*36];            // [key][dh], pad 36 (2-way free)
    __shared__ __bf16 Vst[32*ATT_PAD];      // [dh][key]
    __shared__ __bf16 Pb[4][32*ATT_PAD];    // per-wave P [q][key]
    int tid = threadIdx.x;
    int wave = tid >> 6, lane = tid & 63;
    int ln = lane & 15, quad = lane >> 4;
    int hb = blockIdx.y * DH;
    int qb = blockIdx.x * 128;

    bf16x8 qf[2];
    #pragma unroll
    for (int g = 0; g < 2; g++)
        qf[g] = *(const bf16x8*)&q[(size_t)(qb + wave*32 + g*16 + ln)*C + hb + quad*8];
    f32x4 oacc[2][2] = {};
    float m_[2][4], l_[2][4];
    #pragma unroll
    for (int g = 0; g < 2; g++)
        #pragma unroll
        for (int r = 0; r < 4; r++) { m_[g][r] = -1e30f; l_[g][r] = 0.f; }

    int srow = tid >> 2, sseg = (tid & 3) * 8;
    for (int kt = 0; kt < NN/64; kt++) {
        int kb = kt * 64;
        __syncthreads();
        *(bf16x8*)&Ks[srow*36 + sseg] = *(const bf16x8*)&k[(size_t)(kb+srow)*C + hb + sseg];
        {
            bf16x8 vv = *(const bf16x8*)&v[(size_t)(kb+srow)*C + hb + sseg];
            #pragma unroll
            for (int j = 0; j < 8; j++) Vst[(sseg+j)*ATT_PAD + srow] = vv[j];
        }
        __syncthreads();
        f32x4 s[2][4];
        #pragma unroll
        for (int sub = 0; sub < 4; sub++) {
            bf16x8 bfr = *(const bf16x8*)&Ks[(sub*16+ln)*36 + quad*8];
            #pragma unroll
            for (int g = 0; g < 2; g++) {
                f32x4 z = {0.f,0.f,0.f,0.f};
                s[g][sub] = __builtin_amdgcn_mfma_f32_16x16x32_bf16(qf[g], bfr, z, 0, 0, 0);
            }
        }
        #pragma unroll
        for (int g = 0; g < 2; g++) {
            float tm[4], al[4], ps[4];
            #pragma unroll
            for (int r = 0; r < 4; r++)
                tm[r] = fmaxf(fmaxf(s[g][0][r], s[g][1][r]), fmaxf(s[g][2][r], s[g][3][r]));
            #pragma unroll
            for (int mask = 1; mask <= 8; mask <<= 1)
                #pragma unroll
                for (int r = 0; r < 4; r++)
                    tm[r] = fmaxf(tm[r], __shfl_xor(tm[r], mask));
            #pragma unroll
            for (int r = 0; r < 4; r++) {
                float nm = fmaxf(m_[g][r], tm[r]);
                al[r] = __builtin_amdgcn_exp2f(m_[g][r] - nm);
                m_[g][r] = nm;
                ps[r] = 0.f;
            }
            #pragma unroll
            for (int sub = 0; sub < 4; sub++)
                #pragma unroll
                for (int r = 0; r < 4; r++) {
                    float p = __builtin_amdgcn_exp2f(s[g][sub][r] - m_[g][r]);
                    s[g][sub][r] = p;
                    ps[r] += p;
                }
            #pragma unroll
            for (int mask = 1; mask <= 8; mask <<= 1)
                #pragma unroll
                for (int r = 0; r < 4; r++)
                    ps[r] += __shfl_xor(ps[r], mask);
            #pragma unroll
            for (int r = 0; r < 4; r++) {
                l_[g][r] = l_[g][r]*al[r] + ps[r];
                oacc[g][0][r] *= al[r];
                oacc[g][1][r] *= al[r];
            }
        }
        __bf16* pw = Pb[wave];
        #pragma unroll
        for (int g = 0; g < 2; g++)
            #pragma unroll
            for (int sub = 0; sub < 4; sub++)
                #pragma unroll
                for (int r = 0; r < 4; r++)
                    pw[(g*16 + quad*4 + r)*ATT_PAD + sub*16 + ln] = (__bf16)s[g][sub][r];
        #pragma unroll
        for (int kt2 = 0; kt2 < 2; kt2++) {
            bf16x8 b0 = *(const bf16x8*)&Vst[ln*ATT_PAD + kt2*32 + quad*8];
            bf16x8 b1 = *(const bf16x8*)&Vst[(16+ln)*ATT_PAD + kt2*32 + quad*8];
            #pragma unroll
            for (int g = 0; g < 2; g++) {
                bf16x8 pa = *(const bf16x8*)&pw[(g*16+ln)*ATT_PAD + kt2*32 + quad*8];
                oacc[g][0] = __builtin_amdgcn_mfma_f32_16x16x32_bf16(pa, b0, oacc[g][0], 0, 0, 0);
                oacc[g][1] = __builtin_amdgcn_mfma_f32_16x16x32_bf16(pa, b1, oacc[g][1], 0, 0, 0);
            }
        }
    }
    #pragma unroll
    for (int g = 0; g < 2; g++)
        #pragma unroll
        for (int r = 0; r < 4; r++) {
            float inv = 1.0f / l_[g][r];
            int row = qb + wave*32 + g*16 + quad*4 + r;
            o[(size_t)row*C + hb + ln]      = oacc[g][0][r] * inv;
            o[(size_t)row*C + hb + 16 + ln] = oacc[g][1][r] * inv;
        }
}

extern "C" void kernel_launch(void* const* d_in, const int* in_sizes, int n_in,
                              void* d_out, int out_size, void* d_ws, size_t ws_size,
                              hipStream_t stream) {
    const float* x      = (const float*)d_in[0];
    const int*   ei     = (const int*)d_in[1];
    const float* lin1_w = (const float*)d_in[2];
    const float* lin1_b = (const float*)d_in[3];
    const float* gin_w1 = (const float*)d_in[4];
    const float* gin_b1 = (const float*)d_in[5];
    const float* gin_w2 = (const float*)d_in[6];
    const float* gin_b2 = (const float*)d_in[7];
    const float* wq = (const float*)d_in[8];
    const float* wk = (const float*)d_in[9];
    const float* wv = (const float*)d_in[10];
    const float* wo = (const float*)d_in[11];
    const float* bq = (const float*)d_in[12];
    const float* bk = (const float*)d_in[13];
    const float* bv = (const float*)d_in[14];
    const float* bo = (const float*)d_in[15];
    const float* bn1_g = (const float*)d_in[16];
    const float* bn1_b = (const float*)d_in[17];
    const float* bn2_g = (const float*)d_in[18];
    const float* bn2_b = (const float*)d_in[19];
    const float* bn3_g = (const float*)d_in[20];
    const float* bn3_b = (const float*)d_in[21];
    const float* mw1 = (const float*)d_in[22];
    const float* mb1 = (const float*)d_in[23];
    const float* mw2 = (const float*)d_in[24];
    const float* mb2 = (const float*)d_in[25];

    const size_t NC = (size_t)NN * C;
    float* bufA = (float*)d_ws;      // h (layer input)
    float* bufB = bufA + NC;
    float* bufC = bufB + NC;
    float* bufD = bufC + NC;
    float* bufE = bufD + NC;         // h1
    float* bufF = bufE + NC;         // attn o / h2
    float* bufG = bufF + NC;         // mlp hidden [NN, 2C]
    float* stats = bufG + 2*NC;      // 9 regions x 2C floats
    // bf16 QKV overlays bufC..bufD (free at qkv time)
    __bf16* Qb = (__bf16*)bufC;
    __bf16* Kb = Qb + NC;
    __bf16* Vb = Kb + NC;

    dim3 blk(256);
    dim3 gemmCC(4, 64);
    dim3 gemmC2(8, 64);

    hipMemsetAsync(stats, 0, 9 * 2 * C * sizeof(float), stream);
    lin1_kernel<<<NN, blk, 0, stream>>>(x, lin1_w, lin1_b, bufA);

    for (int l = 0; l < NL; l++) {
        const float* gw1 = gin_w1 + (size_t)l*C*C;
        const float* gb1 = gin_b1 + (size_t)l*C;
        const float* gw2 = gin_w2 + (size_t)l*C*C;
        const float* gb2 = gin_b2 + (size_t)l*C;
        const float* lwq = wq + (size_t)l*C*C; const float* lbq = bq + (size_t)l*C;
        const float* lwk = wk + (size_t)l*C*C; const float* lbk = bk + (size_t)l*C;
        const float* lwv = wv + (size_t)l*C*C; const float* lbv = bv + (size_t)l*C;
        const float* lwo = wo + (size_t)l*C*C; const float* lbo = bo + (size_t)l*C;
        const float* lmw1 = mw1 + (size_t)l*2*C*C; const float* lmb1 = mb1 + (size_t)l*2*C;
        const float* lmw2 = mw2 + (size_t)l*2*C*C; const float* lmb2 = mb2 + (size_t)l*C;
        float* st1 = stats + (size_t)l*3*2*C;
        float* st2 = st1 + 2*C;
        float* st3 = st2 + 2*C;

        // ---- GIN branch ----
        hipMemsetAsync(bufB, 0, NC*sizeof(float), stream);
        scatter_kernel<<<NE, blk, 0, stream>>>(bufA, ei, bufB);
        gemm_bf16<<<gemmCC, blk, 0, stream>>>(bufA, bufB, gw1, gb1, nullptr, nullptr, bufC, nullptr, C, C, 1);
        gemm_bf16<<<gemmCC, blk, 0, stream>>>(bufC, nullptr, gw2, gb2, bufA, nullptr, bufD, st1, C, C, 0);
        bn_apply_kernel<<<NN, blk, 0, stream>>>(bufD, st1, bn1_g + (size_t)l*C, bn1_b + (size_t)l*C, bufE);

        // ---- attention branch ----
        qkv_gemm<<<dim3(4, 64, 3), blk, 0, stream>>>(bufA, lwq, lwk, lwv, lbq, lbk, lbv, Qb, Kb, Vb);
        attn_kernel<<<dim3(NN/128, NH), blk, 0, stream>>>(Qb, Kb, Vb, bufF);
        gemm_bf16<<<gemmCC, blk, 0, stream>>>(bufF, nullptr, lwo, lbo, bufA, nullptr, bufB, st2, C, C, 0);
        bn_apply_kernel<<<NN, blk, 0, stream>>>(bufB, st2, bn2_g + (size_t)l*C, bn2_b + (size_t)l*C, bufF);

        // ---- feedforward ----
        gemm_bf16<<<gemmC2, blk, 0, stream>>>(bufE, bufF, lmw1, lmb1, nullptr, nullptr, bufG, nullptr, C, 2*C, 1);
        gemm_bf16<<<gemmCC, blk, 0, stream>>>(bufG, nullptr, lmw2, lmb2, bufE, bufF, bufB, st3, 2*C, C, 0);
        float* hout = (l == NL-1) ? (float*)d_out : bufA;
        bn_apply_kernel<<<NN, blk, 0, stream>>>(bufB, st3, bn3_g + (size_t)l*C, bn3_b + (size_t)l*C, hout);
    }
}

// Round 4
// 887.274 us; speedup vs baseline: 4.5261x; 1.1133x over previous
//
#include <hip/hip_runtime.h>

#define NN 4096
#define NE 65536
#define C 256
#define NL 3
#define NH 8
#define DH 32
#define EPS 1e-5f
#define SPLIT 4          // key-dim split for attention occupancy
#define KT_PER (NN/64/SPLIT)

typedef __bf16 bf16x8 __attribute__((ext_vector_type(8)));
typedef float f32x4 __attribute__((ext_vector_type(4)));

// scale * log2(e), folded into Q at projection time so softmax uses exp2
#define QSCALE (0.17677669529663687f * 1.4426950408889634f)

// ---------------- lin1: h[n,c] = x[n]*w[c] + b[c] ----------------
__global__ __launch_bounds__(256) void lin1_kernel(const float* __restrict__ x,
        const float* __restrict__ w, const float* __restrict__ b,
        float* __restrict__ out) {
    int n = blockIdx.x, c = threadIdx.x;
    out[(size_t)n*C + c] = x[n]*w[c] + b[c];
}

// ---------------- scatter: agg[dst] += xin[src] ----------------
__global__ __launch_bounds__(256) void scatter_kernel(const float* __restrict__ xin,
        const int* __restrict__ ei, float* __restrict__ agg) {
    int e = blockIdx.x, c = threadIdx.x;
    int src = ei[e];
    int dst = ei[NE + e];
    atomicAdd(&agg[(size_t)dst*C + c], xin[(size_t)src*C + c]);
}

// ---------------- bf16 MFMA GEMM ----------------
#define GS 72   // LDS row stride in bf16 (144B = 36 banks -> 2-way, free)
__global__ __launch_bounds__(256) void gemm_bf16(const float* __restrict__ A,
        const float* __restrict__ A2, const float* __restrict__ W,
        const float* __restrict__ bias, const float* __restrict__ add1,
        const float* __restrict__ add2, float* __restrict__ out,
        float* __restrict__ stats, int K, int Nout, int relu) {
    __shared__ __bf16 As[64*GS];
    __shared__ __bf16 Ws[64*GS];
    int tid = threadIdx.x;
    int wave = tid >> 6, lane = tid & 63;
    int ln = lane & 15, quad = lane >> 4;
    int bm = blockIdx.y * 64, bn = blockIdx.x * 64;
    int row = tid >> 2, kseg = (tid & 3) * 16;
    f32x4 acc[4] = {};
    for (int k0 = 0; k0 < K; k0 += 64) {
        __syncthreads();
        {
            const float* ap = &A[(size_t)(bm+row)*K + k0 + kseg];
            __bf16 bt[16];
            if (A2) {
                const float* ap2 = &A2[(size_t)(bm+row)*K + k0 + kseg];
                #pragma unroll
                for (int i = 0; i < 4; i++) {
                    float4 t = *(const float4*)(ap + i*4);
                    float4 t2 = *(const float4*)(ap2 + i*4);
                    bt[i*4+0] = (__bf16)(t.x+t2.x); bt[i*4+1] = (__bf16)(t.y+t2.y);
                    bt[i*4+2] = (__bf16)(t.z+t2.z); bt[i*4+3] = (__bf16)(t.w+t2.w);
                }
            } else {
                #pragma unroll
                for (int i = 0; i < 4; i++) {
                    float4 t = *(const float4*)(ap + i*4);
                    bt[i*4+0] = (__bf16)t.x; bt[i*4+1] = (__bf16)t.y;
                    bt[i*4+2] = (__bf16)t.z; bt[i*4+3] = (__bf16)t.w;
                }
            }
            *(bf16x8*)&As[row*GS + kseg]     = *(bf16x8*)&bt[0];
            *(bf16x8*)&As[row*GS + kseg + 8] = *(bf16x8*)&bt[8];
            const float* wp = &W[(size_t)(bn+row)*K + k0 + kseg];
            #pragma unroll
            for (int i = 0; i < 4; i++) {
                float4 t = *(const float4*)(wp + i*4);
                bt[i*4+0] = (__bf16)t.x; bt[i*4+1] = (__bf16)t.y;
                bt[i*4+2] = (__bf16)t.z; bt[i*4+3] = (__bf16)t.w;
            }
            *(bf16x8*)&Ws[row*GS + kseg]     = *(bf16x8*)&bt[0];
            *(bf16x8*)&Ws[row*GS + kseg + 8] = *(bf16x8*)&bt[8];
        }
        __syncthreads();
        #pragma unroll
        for (int kt2 = 0; kt2 < 2; kt2++) {
            bf16x8 bfr = *(const bf16x8*)&Ws[(wave*16+ln)*GS + kt2*32 + quad*8];
            #pragma unroll
            for (int i = 0; i < 4; i++) {
                bf16x8 afr = *(const bf16x8*)&As[(i*16+ln)*GS + kt2*32 + quad*8];
                acc[i] = __builtin_amdgcn_mfma_f32_16x16x32_bf16(afr, bfr, acc[i], 0, 0, 0);
            }
        }
    }
    int col = bn + wave*16 + ln;
    float bsv = bias[col];
    float ssum = 0.f, ssq = 0.f;
    #pragma unroll
    for (int i = 0; i < 4; i++) {
        #pragma unroll
        for (int r = 0; r < 4; r++) {
            int rw = bm + i*16 + quad*4 + r;
            float vv = acc[i][r] + bsv;
            if (relu) vv = fmaxf(vv, 0.f);
            size_t idx = (size_t)rw*Nout + col;
            if (add1) vv += add1[idx];
            if (add2) vv += add2[idx];
            out[idx] = vv;
            ssum += vv; ssq += vv*vv;
        }
    }
    if (stats) {
        ssum += __shfl_xor(ssum, 16); ssum += __shfl_xor(ssum, 32);
        ssq  += __shfl_xor(ssq, 16);  ssq  += __shfl_xor(ssq, 32);
        if (quad == 0) {
            atomicAdd(&stats[col], ssum);
            atomicAdd(&stats[Nout + col], ssq);
        }
    }
}

// ---------------- fused QKV projection, bf16 outputs ----------------
__global__ __launch_bounds__(256) void qkv_gemm(const float* __restrict__ A,
        const float* __restrict__ wq, const float* __restrict__ wk,
        const float* __restrict__ wv, const float* __restrict__ bq,
        const float* __restrict__ bk, const float* __restrict__ bv,
        __bf16* __restrict__ qo, __bf16* __restrict__ ko,
        __bf16* __restrict__ vo) {
    int z = blockIdx.z;
    const float* W    = z == 0 ? wq : (z == 1 ? wk : wv);
    const float* bias = z == 0 ? bq : (z == 1 ? bk : bv);
    __bf16* out       = z == 0 ? qo : (z == 1 ? ko : vo);
    float oscale      = z == 0 ? QSCALE : 1.0f;
    __shared__ __bf16 As[64*GS];
    __shared__ __bf16 Ws[64*GS];
    int tid = threadIdx.x;
    int wave = tid >> 6, lane = tid & 63;
    int ln = lane & 15, quad = lane >> 4;
    int bm = blockIdx.y * 64, bn = blockIdx.x * 64;
    int row = tid >> 2, kseg = (tid & 3) * 16;
    f32x4 acc[4] = {};
    for (int k0 = 0; k0 < C; k0 += 64) {
        __syncthreads();
        {
            __bf16 bt[16];
            const float* ap = &A[(size_t)(bm+row)*C + k0 + kseg];
            #pragma unroll
            for (int i = 0; i < 4; i++) {
                float4 t = *(const float4*)(ap + i*4);
                bt[i*4+0] = (__bf16)t.x; bt[i*4+1] = (__bf16)t.y;
                bt[i*4+2] = (__bf16)t.z; bt[i*4+3] = (__bf16)t.w;
            }
            *(bf16x8*)&As[row*GS + kseg]     = *(bf16x8*)&bt[0];
            *(bf16x8*)&As[row*GS + kseg + 8] = *(bf16x8*)&bt[8];
            const float* wp = &W[(size_t)(bn+row)*C + k0 + kseg];
            #pragma unroll
            for (int i = 0; i < 4; i++) {
                float4 t = *(const float4*)(wp + i*4);
                bt[i*4+0] = (__bf16)t.x; bt[i*4+1] = (__bf16)t.y;
                bt[i*4+2] = (__bf16)t.z; bt[i*4+3] = (__bf16)t.w;
            }
            *(bf16x8*)&Ws[row*GS + kseg]     = *(bf16x8*)&bt[0];
            *(bf16x8*)&Ws[row*GS + kseg + 8] = *(bf16x8*)&bt[8];
        }
        __syncthreads();
        #pragma unroll
        for (int kt2 = 0; kt2 < 2; kt2++) {
            bf16x8 bfr = *(const bf16x8*)&Ws[(wave*16+ln)*GS + kt2*32 + quad*8];
            #pragma unroll
            for (int i = 0; i < 4; i++) {
                bf16x8 afr = *(const bf16x8*)&As[(i*16+ln)*GS + kt2*32 + quad*8];
                acc[i] = __builtin_amdgcn_mfma_f32_16x16x32_bf16(afr, bfr, acc[i], 0, 0, 0);
            }
        }
    }
    int col = bn + wave*16 + ln;
    float bsv = bias[col];
    #pragma unroll
    for (int i = 0; i < 4; i++)
        #pragma unroll
        for (int r = 0; r < 4; r++) {
            int rw = bm + i*16 + quad*4 + r;
            out[(size_t)rw*C + col] = (__bf16)((acc[i][r] + bsv) * oscale);
        }
}

// ---------------- BatchNorm apply ----------------
__global__ __launch_bounds__(256) void bn_apply_kernel(const float* __restrict__ in,
        const float* __restrict__ stats, const float* __restrict__ g,
        const float* __restrict__ b, float* __restrict__ out) {
    int c = threadIdx.x;
    int n = blockIdx.x;
    float mean = stats[c] * (1.0f/NN);
    float var  = stats[C + c] * (1.0f/NN) - mean*mean;
    float sc = rsqrtf(var + EPS) * g[c];
    out[(size_t)n*C + c] = (in[(size_t)n*C + c] - mean) * sc + b[c];
}

// ---------------- bf16 MFMA flash attention, key-split ----------------
// grid (NN/128, NH, SPLIT), 256 thr = 4 waves; wave owns 32 q-rows.
// Split z handles keys [z*NN/SPLIT, (z+1)*NN/SPLIT). Writes normalized
// partial O (bf16) + per-row (m, l) in exp2 domain; combine merges splits.
#define ATT_PAD 72
__global__ __launch_bounds__(256) void attn_kernel(const __bf16* __restrict__ q,
        const __bf16* __restrict__ k, const __bf16* __restrict__ v,
        __bf16* __restrict__ opart, float2* __restrict__ ml) {
    __shared__ __bf16 Ks[64*36];            // [key][dh], pad 36 (2-way free)
    __shared__ __bf16 Vst[32*ATT_PAD];      // [dh][key]
    __shared__ __bf16 Pb[4][32*ATT_PAD];    // per-wave P [q][key]
    int tid = threadIdx.x;
    int wave = tid >> 6, lane = tid & 63;
    int ln = lane & 15, quad = lane >> 4;
    int head = blockIdx.y;
    int hb = head * DH;
    int qb = blockIdx.x * 128;
    int z = blockIdx.z;

    bf16x8 qf[2];
    #pragma unroll
    for (int g = 0; g < 2; g++)
        qf[g] = *(const bf16x8*)&q[(size_t)(qb + wave*32 + g*16 + ln)*C + hb + quad*8];
    f32x4 oacc[2][2] = {};
    float m_[2][4], l_[2][4];
    #pragma unroll
    for (int g = 0; g < 2; g++)
        #pragma unroll
        for (int r = 0; r < 4; r++) { m_[g][r] = -1e30f; l_[g][r] = 0.f; }

    int srow = tid >> 2, sseg = (tid & 3) * 8;
    for (int kt = z*KT_PER; kt < (z+1)*KT_PER; kt++) {
        int kb = kt * 64;
        __syncthreads();
        *(bf16x8*)&Ks[srow*36 + sseg] = *(const bf16x8*)&k[(size_t)(kb+srow)*C + hb + sseg];
        {
            bf16x8 vv = *(const bf16x8*)&v[(size_t)(kb+srow)*C + hb + sseg];
            #pragma unroll
            for (int j = 0; j < 8; j++) Vst[(sseg+j)*ATT_PAD + srow] = vv[j];
        }
        __syncthreads();
        f32x4 s[2][4];
        #pragma unroll
        for (int sub = 0; sub < 4; sub++) {
            bf16x8 bfr = *(const bf16x8*)&Ks[(sub*16+ln)*36 + quad*8];
            #pragma unroll
            for (int g = 0; g < 2; g++) {
                f32x4 zz = {0.f,0.f,0.f,0.f};
                s[g][sub] = __builtin_amdgcn_mfma_f32_16x16x32_bf16(qf[g], bfr, zz, 0, 0, 0);
            }
        }
        #pragma unroll
        for (int g = 0; g < 2; g++) {
            float tm[4], al[4], ps[4];
            #pragma unroll
            for (int r = 0; r < 4; r++)
                tm[r] = fmaxf(fmaxf(s[g][0][r], s[g][1][r]), fmaxf(s[g][2][r], s[g][3][r]));
            #pragma unroll
            for (int mask = 1; mask <= 8; mask <<= 1)
                #pragma unroll
                for (int r = 0; r < 4; r++)
                    tm[r] = fmaxf(tm[r], __shfl_xor(tm[r], mask));
            #pragma unroll
            for (int r = 0; r < 4; r++) {
                float nm = fmaxf(m_[g][r], tm[r]);
                al[r] = __builtin_amdgcn_exp2f(m_[g][r] - nm);
                m_[g][r] = nm;
                ps[r] = 0.f;
            }
            #pragma unroll
            for (int sub = 0; sub < 4; sub++)
                #pragma unroll
                for (int r = 0; r < 4; r++) {
                    float p = __builtin_amdgcn_exp2f(s[g][sub][r] - m_[g][r]);
                    s[g][sub][r] = p;
                    ps[r] += p;
                }
            #pragma unroll
            for (int mask = 1; mask <= 8; mask <<= 1)
                #pragma unroll
                for (int r = 0; r < 4; r++)
                    ps[r] += __shfl_xor(ps[r], mask);
            #pragma unroll
            for (int r = 0; r < 4; r++) {
                l_[g][r] = l_[g][r]*al[r] + ps[r];
                oacc[g][0][r] *= al[r];
                oacc[g][1][r] *= al[r];
            }
        }
        __bf16* pw = Pb[wave];
        #pragma unroll
        for (int g = 0; g < 2; g++)
            #pragma unroll
            for (int sub = 0; sub < 4; sub++)
                #pragma unroll
                for (int r = 0; r < 4; r++)
                    pw[(g*16 + quad*4 + r)*ATT_PAD + sub*16 + ln] = (__bf16)s[g][sub][r];
        #pragma unroll
        for (int kt2 = 0; kt2 < 2; kt2++) {
            bf16x8 b0 = *(const bf16x8*)&Vst[ln*ATT_PAD + kt2*32 + quad*8];
            bf16x8 b1 = *(const bf16x8*)&Vst[(16+ln)*ATT_PAD + kt2*32 + quad*8];
            #pragma unroll
            for (int g = 0; g < 2; g++) {
                bf16x8 pa = *(const bf16x8*)&pw[(g*16+ln)*ATT_PAD + kt2*32 + quad*8];
                oacc[g][0] = __builtin_amdgcn_mfma_f32_16x16x32_bf16(pa, b0, oacc[g][0], 0, 0, 0);
                oacc[g][1] = __builtin_amdgcn_mfma_f32_16x16x32_bf16(pa, b1, oacc[g][1], 0, 0, 0);
            }
        }
    }
    #pragma unroll
    for (int g = 0; g < 2; g++)
        #pragma unroll
        for (int r = 0; r < 4; r++) {
            float inv = 1.0f / l_[g][r];
            int row = qb + wave*32 + g*16 + quad*4 + r;
            size_t base = ((size_t)z*NN + row)*C + hb;
            opart[base + ln]      = (__bf16)(oacc[g][0][r] * inv);
            opart[base + 16 + ln] = (__bf16)(oacc[g][1][r] * inv);
            if (ln == 0)
                ml[((size_t)z*NH + head)*NN + row] = make_float2(m_[g][r], l_[g][r]);
        }
}

// ---------------- combine split-K attention partials ----------------
__global__ __launch_bounds__(256) void attn_combine(const __bf16* __restrict__ opart,
        const float2* __restrict__ ml, float* __restrict__ o) {
    int row = blockIdx.x, c = threadIdx.x;
    int head = c >> 5;
    float2 t[SPLIT];
    float M = -1e30f;
    #pragma unroll
    for (int z = 0; z < SPLIT; z++) {
        t[z] = ml[((size_t)z*NH + head)*NN + row];
        M = fmaxf(M, t[z].x);
    }
    float acc = 0.f, wsum = 0.f;
    #pragma unroll
    for (int z = 0; z < SPLIT; z++) {
        float w = t[z].y * __builtin_amdgcn_exp2f(t[z].x - M);
        acc += w * (float)opart[((size_t)z*NN + row)*C + c];
        wsum += w;
    }
    o[(size_t)row*C + c] = acc / wsum;
}

extern "C" void kernel_launch(void* const* d_in, const int* in_sizes, int n_in,
                              void* d_out, int out_size, void* d_ws, size_t ws_size,
                              hipStream_t stream) {
    const float* x      = (const float*)d_in[0];
    const int*   ei     = (const int*)d_in[1];
    const float* lin1_w = (const float*)d_in[2];
    const float* lin1_b = (const float*)d_in[3];
    const float* gin_w1 = (const float*)d_in[4];
    const float* gin_b1 = (const float*)d_in[5];
    const float* gin_w2 = (const float*)d_in[6];
    const float* gin_b2 = (const float*)d_in[7];
    const float* wq = (const float*)d_in[8];
    const float* wk = (const float*)d_in[9];
    const float* wv = (const float*)d_in[10];
    const float* wo = (const float*)d_in[11];
    const float* bq = (const float*)d_in[12];
    const float* bk = (const float*)d_in[13];
    const float* bv = (const float*)d_in[14];
    const float* bo = (const float*)d_in[15];
    const float* bn1_g = (const float*)d_in[16];
    const float* bn1_b = (const float*)d_in[17];
    const float* bn2_g = (const float*)d_in[18];
    const float* bn2_b = (const float*)d_in[19];
    const float* bn3_g = (const float*)d_in[20];
    const float* bn3_b = (const float*)d_in[21];
    const float* mw1 = (const float*)d_in[22];
    const float* mb1 = (const float*)d_in[23];
    const float* mw2 = (const float*)d_in[24];
    const float* mb2 = (const float*)d_in[25];

    const size_t NC = (size_t)NN * C;
    float* bufA = (float*)d_ws;      // h (layer input)
    float* bufB = bufA + NC;         // agg; later ml partials; later gemm out
    float* bufC = bufB + NC;
    float* bufD = bufC + NC;
    float* bufE = bufD + NC;         // h1
    float* bufF = bufE + NC;         // attn o / h2
    float* bufG = bufF + NC;         // mlp hidden [NN,2C]; Opart during attn
    float* stats = bufG + 2*NC;      // 9 regions x 2C floats
    // bf16 QKV overlays bufC..bufD (free at qkv time)
    __bf16* Qb = (__bf16*)bufC;
    __bf16* Kb = Qb + NC;
    __bf16* Vb = Kb + NC;
    __bf16* Opart = (__bf16*)bufG;   // SPLIT*NN*C bf16 = 8 MB = bufG exactly
    float2* Oml = (float2*)bufB;     // SPLIT*NH*NN float2 = 1 MB

    dim3 blk(256);
    dim3 gemmCC(4, 64);
    dim3 gemmC2(8, 64);

    hipMemsetAsync(stats, 0, 9 * 2 * C * sizeof(float), stream);
    lin1_kernel<<<NN, blk, 0, stream>>>(x, lin1_w, lin1_b, bufA);

    for (int l = 0; l < NL; l++) {
        const float* gw1 = gin_w1 + (size_t)l*C*C;
        const float* gb1 = gin_b1 + (size_t)l*C;
        const float* gw2 = gin_w2 + (size_t)l*C*C;
        const float* gb2 = gin_b2 + (size_t)l*C;
        const float* lwq = wq + (size_t)l*C*C; const float* lbq = bq + (size_t)l*C;
        const float* lwk = wk + (size_t)l*C*C; const float* lbk = bk + (size_t)l*C;
        const float* lwv = wv + (size_t)l*C*C; const float* lbv = bv + (size_t)l*C;
        const float* lwo = wo + (size_t)l*C*C; const float* lbo = bo + (size_t)l*C;
        const float* lmw1 = mw1 + (size_t)l*2*C*C; const float* lmb1 = mb1 + (size_t)l*2*C;
        const float* lmw2 = mw2 + (size_t)l*2*C*C; const float* lmb2 = mb2 + (size_t)l*C;
        float* st1 = stats + (size_t)l*3*2*C;
        float* st2 = st1 + 2*C;
        float* st3 = st2 + 2*C;

        // ---- GIN branch ----
        hipMemsetAsync(bufB, 0, NC*sizeof(float), stream);
        scatter_kernel<<<NE, blk, 0, stream>>>(bufA, ei, bufB);
        gemm_bf16<<<gemmCC, blk, 0, stream>>>(bufA, bufB, gw1, gb1, nullptr, nullptr, bufC, nullptr, C, C, 1);
        gemm_bf16<<<gemmCC, blk, 0, stream>>>(bufC, nullptr, gw2, gb2, bufA, nullptr, bufD, st1, C, C, 0);
        bn_apply_kernel<<<NN, blk, 0, stream>>>(bufD, st1, bn1_g + (size_t)l*C, bn1_b + (size_t)l*C, bufE);

        // ---- attention branch (bufB free after gemm1; bufG free here) ----
        qkv_gemm<<<dim3(4, 64, 3), blk, 0, stream>>>(bufA, lwq, lwk, lwv, lbq, lbk, lbv, Qb, Kb, Vb);
        attn_kernel<<<dim3(NN/128, NH, SPLIT), blk, 0, stream>>>(Qb, Kb, Vb, Opart, Oml);
        attn_combine<<<NN, blk, 0, stream>>>(Opart, Oml, bufF);
        gemm_bf16<<<gemmCC, blk, 0, stream>>>(bufF, nullptr, lwo, lbo, bufA, nullptr, bufB, st2, C, C, 0);
        bn_apply_kernel<<<NN, blk, 0, stream>>>(bufB, st2, bn2_g + (size_t)l*C, bn2_b + (size_t)l*C, bufF);

        // ---- feedforward ----
        gemm_bf16<<<gemmC2, blk, 0, stream>>>(bufE, bufF, lmw1, lmb1, nullptr, nullptr, bufG, nullptr, C, 2*C, 1);
        gemm_bf16<<<gemmCC, blk, 0, stream>>>(bufG, nullptr, lmw2, lmb2, bufE, bufF, bufB, st3, 2*C, C, 0);
        float* hout = (l == NL-1) ? (float*)d_out : bufA;
        bn_apply_kernel<<<NN, blk, 0, stream>>>(bufB, st3, bn3_g + (size_t)l*C, bn3_b + (size_t)l*C, hout);
    }
}

// Round 5
// 767.096 us; speedup vs baseline: 5.2352x; 1.1567x over previous
//
#include <hip/hip_runtime.h>

#define NN 4096
#define NE 65536
#define C 256
#define NL 3
#define NH 8
#define DH 32
#define EPS 1e-5f
#define SPLIT 4          // key-dim split for attention occupancy
#define KT_PER (NN/64/SPLIT)

typedef __bf16 bf16x8 __attribute__((ext_vector_type(8)));
typedef float f32x4 __attribute__((ext_vector_type(4)));
typedef short bf16x4s __attribute__((ext_vector_type(4)));   // 4 bf16 as i16x4

// scale * log2(e), folded into Q at projection time so softmax uses exp2
#define QSCALE (0.17677669529663687f * 1.4426950408889634f)

// ---------------- lin1: h[n,c] = x[n]*w[c] + b[c] ----------------
__global__ __launch_bounds__(256) void lin1_kernel(const float* __restrict__ x,
        const float* __restrict__ w, const float* __restrict__ b,
        float* __restrict__ out) {
    int n = blockIdx.x, c = threadIdx.x;
    out[(size_t)n*C + c] = x[n]*w[c] + b[c];
}

// ---------------- scatter: agg[dst] += xin[src] ----------------
__global__ __launch_bounds__(256) void scatter_kernel(const float* __restrict__ xin,
        const int* __restrict__ ei, float* __restrict__ agg) {
    int e = blockIdx.x, c = threadIdx.x;
    int src = ei[e];
    int dst = ei[NE + e];
    atomicAdd(&agg[(size_t)dst*C + c], xin[(size_t)src*C + c]);
}

// ---------------- bf16 MFMA GEMM ----------------
#define GS 72   // LDS row stride in bf16 (144B = 36 banks -> 2-way, free)
__global__ __launch_bounds__(256) void gemm_bf16(const float* __restrict__ A,
        const float* __restrict__ A2, const float* __restrict__ W,
        const float* __restrict__ bias, const float* __restrict__ add1,
        const float* __restrict__ add2, float* __restrict__ out,
        float* __restrict__ stats, int K, int Nout, int relu) {
    __shared__ __bf16 As[64*GS];
    __shared__ __bf16 Ws[64*GS];
    int tid = threadIdx.x;
    int wave = tid >> 6, lane = tid & 63;
    int ln = lane & 15, quad = lane >> 4;
    int bm = blockIdx.y * 64, bn = blockIdx.x * 64;
    int row = tid >> 2, kseg = (tid & 3) * 16;
    f32x4 acc[4] = {};
    for (int k0 = 0; k0 < K; k0 += 64) {
        __syncthreads();
        {
            const float* ap = &A[(size_t)(bm+row)*K + k0 + kseg];
            __bf16 bt[16];
            if (A2) {
                const float* ap2 = &A2[(size_t)(bm+row)*K + k0 + kseg];
                #pragma unroll
                for (int i = 0; i < 4; i++) {
                    float4 t = *(const float4*)(ap + i*4);
                    float4 t2 = *(const float4*)(ap2 + i*4);
                    bt[i*4+0] = (__bf16)(t.x+t2.x); bt[i*4+1] = (__bf16)(t.y+t2.y);
                    bt[i*4+2] = (__bf16)(t.z+t2.z); bt[i*4+3] = (__bf16)(t.w+t2.w);
                }
            } else {
                #pragma unroll
                for (int i = 0; i < 4; i++) {
                    float4 t = *(const float4*)(ap + i*4);
                    bt[i*4+0] = (__bf16)t.x; bt[i*4+1] = (__bf16)t.y;
                    bt[i*4+2] = (__bf16)t.z; bt[i*4+3] = (__bf16)t.w;
                }
            }
            *(bf16x8*)&As[row*GS + kseg]     = *(bf16x8*)&bt[0];
            *(bf16x8*)&As[row*GS + kseg + 8] = *(bf16x8*)&bt[8];
            const float* wp = &W[(size_t)(bn+row)*K + k0 + kseg];
            #pragma unroll
            for (int i = 0; i < 4; i++) {
                float4 t = *(const float4*)(wp + i*4);
                bt[i*4+0] = (__bf16)t.x; bt[i*4+1] = (__bf16)t.y;
                bt[i*4+2] = (__bf16)t.z; bt[i*4+3] = (__bf16)t.w;
            }
            *(bf16x8*)&Ws[row*GS + kseg]     = *(bf16x8*)&bt[0];
            *(bf16x8*)&Ws[row*GS + kseg + 8] = *(bf16x8*)&bt[8];
        }
        __syncthreads();
        #pragma unroll
        for (int kt2 = 0; kt2 < 2; kt2++) {
            bf16x8 bfr = *(const bf16x8*)&Ws[(wave*16+ln)*GS + kt2*32 + quad*8];
            #pragma unroll
            for (int i = 0; i < 4; i++) {
                bf16x8 afr = *(const bf16x8*)&As[(i*16+ln)*GS + kt2*32 + quad*8];
                acc[i] = __builtin_amdgcn_mfma_f32_16x16x32_bf16(afr, bfr, acc[i], 0, 0, 0);
            }
        }
    }
    int col = bn + wave*16 + ln;
    float bsv = bias[col];
    float ssum = 0.f, ssq = 0.f;
    #pragma unroll
    for (int i = 0; i < 4; i++) {
        #pragma unroll
        for (int r = 0; r < 4; r++) {
            int rw = bm + i*16 + quad*4 + r;
            float vv = acc[i][r] + bsv;
            if (relu) vv = fmaxf(vv, 0.f);
            size_t idx = (size_t)rw*Nout + col;
            if (add1) vv += add1[idx];
            if (add2) vv += add2[idx];
            out[idx] = vv;
            ssum += vv; ssq += vv*vv;
        }
    }
    if (stats) {
        ssum += __shfl_xor(ssum, 16); ssum += __shfl_xor(ssum, 32);
        ssq  += __shfl_xor(ssq, 16);  ssq  += __shfl_xor(ssq, 32);
        if (quad == 0) {
            atomicAdd(&stats[col], ssum);
            atomicAdd(&stats[Nout + col], ssq);
        }
    }
}

// ---------------- fused QKV projection, bf16 outputs ----------------
__global__ __launch_bounds__(256) void qkv_gemm(const float* __restrict__ A,
        const float* __restrict__ wq, const float* __restrict__ wk,
        const float* __restrict__ wv, const float* __restrict__ bq,
        const float* __restrict__ bk, const float* __restrict__ bv,
        __bf16* __restrict__ qo, __bf16* __restrict__ ko,
        __bf16* __restrict__ vo) {
    int z = blockIdx.z;
    const float* W    = z == 0 ? wq : (z == 1 ? wk : wv);
    const float* bias = z == 0 ? bq : (z == 1 ? bk : bv);
    __bf16* out       = z == 0 ? qo : (z == 1 ? ko : vo);
    float oscale      = z == 0 ? QSCALE : 1.0f;
    __shared__ __bf16 As[64*GS];
    __shared__ __bf16 Ws[64*GS];
    int tid = threadIdx.x;
    int wave = tid >> 6, lane = tid & 63;
    int ln = lane & 15, quad = lane >> 4;
    int bm = blockIdx.y * 64, bn = blockIdx.x * 64;
    int row = tid >> 2, kseg = (tid & 3) * 16;
    f32x4 acc[4] = {};
    for (int k0 = 0; k0 < C; k0 += 64) {
        __syncthreads();
        {
            __bf16 bt[16];
            const float* ap = &A[(size_t)(bm+row)*C + k0 + kseg];
            #pragma unroll
            for (int i = 0; i < 4; i++) {
                float4 t = *(const float4*)(ap + i*4);
                bt[i*4+0] = (__bf16)t.x; bt[i*4+1] = (__bf16)t.y;
                bt[i*4+2] = (__bf16)t.z; bt[i*4+3] = (__bf16)t.w;
            }
            *(bf16x8*)&As[row*GS + kseg]     = *(bf16x8*)&bt[0];
            *(bf16x8*)&As[row*GS + kseg + 8] = *(bf16x8*)&bt[8];
            const float* wp = &W[(size_t)(bn+row)*C + k0 + kseg];
            #pragma unroll
            for (int i = 0; i < 4; i++) {
                float4 t = *(const float4*)(wp + i*4);
                bt[i*4+0] = (__bf16)t.x; bt[i*4+1] = (__bf16)t.y;
                bt[i*4+2] = (__bf16)t.z; bt[i*4+3] = (__bf16)t.w;
            }
            *(bf16x8*)&Ws[row*GS + kseg]     = *(bf16x8*)&bt[0];
            *(bf16x8*)&Ws[row*GS + kseg + 8] = *(bf16x8*)&bt[8];
        }
        __syncthreads();
        #pragma unroll
        for (int kt2 = 0; kt2 < 2; kt2++) {
            bf16x8 bfr = *(const bf16x8*)&Ws[(wave*16+ln)*GS + kt2*32 + quad*8];
            #pragma unroll
            for (int i = 0; i < 4; i++) {
                bf16x8 afr = *(const bf16x8*)&As[(i*16+ln)*GS + kt2*32 + quad*8];
                acc[i] = __builtin_amdgcn_mfma_f32_16x16x32_bf16(afr, bfr, acc[i], 0, 0, 0);
            }
        }
    }
    int col = bn + wave*16 + ln;
    float bsv = bias[col];
    #pragma unroll
    for (int i = 0; i < 4; i++)
        #pragma unroll
        for (int r = 0; r < 4; r++) {
            int rw = bm + i*16 + quad*4 + r;
            out[(size_t)rw*C + col] = (__bf16)((acc[i][r] + bsv) * oscale);
        }
}

// ---------------- BatchNorm apply ----------------
__global__ __launch_bounds__(256) void bn_apply_kernel(const float* __restrict__ in,
        const float* __restrict__ stats, const float* __restrict__ g,
        const float* __restrict__ b, float* __restrict__ out) {
    int c = threadIdx.x;
    int n = blockIdx.x;
    float mean = stats[c] * (1.0f/NN);
    float var  = stats[C + c] * (1.0f/NN) - mean*mean;
    float sc = rsqrtf(var + EPS) * g[c];
    out[(size_t)n*C + c] = (in[(size_t)n*C + c] - mean) * sc + b[c];
}

// ---------------- bf16 MFMA flash attention, S^T formulation ----------------
// grid (NN/128, NH, SPLIT), 256 thr = 4 waves; wave owns 32 queries (2 groups
// of 16 on ln). S^T = K·Q^T via mfma_16x16x32 (A=K-frag from LDS, B=Q-frag in
// regs) -> S^T[key=quad*4+r (per 16-key sub)][query=ln]. That register layout
// IS the A-operand layout of mfma_16x16x16_bf16 (A[m=ln][k=quad*4+j]), so P
// feeds PV directly from registers — no LDS round-trip. V B-frags
// (B[k=quad*4+j][n=ln]) load straight from global (L2-hot, issued early).
// Softmax state (m,l) is per-lane (query=ln), reduced over keys by 2 shuffles.
__global__ __launch_bounds__(256) void attn_kernel(const __bf16* __restrict__ q,
        const __bf16* __restrict__ k, const __bf16* __restrict__ v,
        __bf16* __restrict__ opart, float2* __restrict__ ml) {
    __shared__ __bf16 Ks[64*36];            // [key][dh], row-major, pad 36
    int tid = threadIdx.x;
    int wave = tid >> 6, lane = tid & 63;
    int ln = lane & 15, quad = lane >> 4;
    int head = blockIdx.y;
    int hb = head * DH;
    int qb = blockIdx.x * 128;
    int z = blockIdx.z;

    // Q fragments (B operand): B[k=dh=quad*8+j][n=query=ln]
    bf16x8 qf[2];
    #pragma unroll
    for (int g = 0; g < 2; g++)
        qf[g] = *(const bf16x8*)&q[(size_t)(qb + wave*32 + g*16 + ln)*C + hb + quad*8];

    // O accumulators: D[m=query=quad*4+r][n=dh=h*16+ln]
    f32x4 oacc[2][2] = {};
    float m_[2], l_[2];
    #pragma unroll
    for (int g = 0; g < 2; g++) { m_[g] = -1e30f; l_[g] = 0.f; }

    int srow = tid >> 2, sseg = (tid & 3) * 8;   // K staging assignment
    for (int kt = z*KT_PER; kt < (z+1)*KT_PER; kt++) {
        int kb = kt * 64;
        // V fragments straight from global (issued early to hide latency):
        // vf[sub][h] holds V[kb+sub*16+quad*4+j][hb+h*16+ln], j=0..3
        union { __bf16 b[4]; bf16x4s s; } vf[4][2];
        {
            const __bf16* vb = v + ((size_t)kb + quad*4)*C + hb + ln;
            #pragma unroll
            for (int sub = 0; sub < 4; sub++)
                #pragma unroll
                for (int h = 0; h < 2; h++)
                    #pragma unroll
                    for (int j = 0; j < 4; j++)
                        vf[sub][h].b[j] = vb[(size_t)(sub*16 + j)*C + h*16];
        }
        __syncthreads();
        *(bf16x8*)&Ks[srow*36 + sseg] = *(const bf16x8*)&k[(size_t)(kb+srow)*C + hb + sseg];
        __syncthreads();

        // S^T: 4 key-subtiles x 2 query groups
        f32x4 st[2][4];
        #pragma unroll
        for (int sub = 0; sub < 4; sub++) {
            bf16x8 af = *(const bf16x8*)&Ks[(sub*16+ln)*36 + quad*8];
            #pragma unroll
            for (int g = 0; g < 2; g++) {
                f32x4 zz = {0.f,0.f,0.f,0.f};
                st[g][sub] = __builtin_amdgcn_mfma_f32_16x16x32_bf16(af, qf[g], zz, 0, 0, 0);
            }
        }
        #pragma unroll
        for (int g = 0; g < 2; g++) {
            // max over the 16 local key-values, then across quads
            float tm = st[g][0][0];
            #pragma unroll
            for (int sub = 0; sub < 4; sub++)
                #pragma unroll
                for (int r = 0; r < 4; r++)
                    tm = fmaxf(tm, st[g][sub][r]);
            tm = fmaxf(tm, __shfl_xor(tm, 16));
            tm = fmaxf(tm, __shfl_xor(tm, 32));
            float nm = fmaxf(m_[g], tm);
            float al = __builtin_amdgcn_exp2f(m_[g] - nm);
            m_[g] = nm;
            float ps = 0.f;
            union { __bf16 b[4]; bf16x4s s; } pf[4];
            #pragma unroll
            for (int sub = 0; sub < 4; sub++)
                #pragma unroll
                for (int r = 0; r < 4; r++) {
                    float p = __builtin_amdgcn_exp2f(st[g][sub][r] - nm);
                    pf[sub].b[r] = (__bf16)p;
                    ps += p;
                }
            ps += __shfl_xor(ps, 16);
            ps += __shfl_xor(ps, 32);
            l_[g] = l_[g]*al + ps;
            // alpha per output row (query quad*4+r): fetch from lane ln=quad*4+r
            #pragma unroll
            for (int r = 0; r < 4; r++) {
                float ar = __shfl(al, (lane & 48) | (quad*4 + r));
                oacc[g][0][r] *= ar;
                oacc[g][1][r] *= ar;
            }
            // PV: P (A-operand, in regs) x V (B-operand, from global)
            #pragma unroll
            for (int sub = 0; sub < 4; sub++) {
                oacc[g][0] = __builtin_amdgcn_mfma_f32_16x16x16bf16_1k(
                        pf[sub].s, vf[sub][0].s, oacc[g][0], 0, 0, 0);
                oacc[g][1] = __builtin_amdgcn_mfma_f32_16x16x16bf16_1k(
                        pf[sub].s, vf[sub][1].s, oacc[g][1], 0, 0, 0);
            }
        }
    }
    #pragma unroll
    for (int g = 0; g < 2; g++) {
        #pragma unroll
        for (int r = 0; r < 4; r++) {
            float lr = __shfl(l_[g], (lane & 48) | (quad*4 + r));
            float inv = 1.0f / lr;
            int row = qb + wave*32 + g*16 + quad*4 + r;
            size_t base = ((size_t)z*NN + row)*C + hb;
            opart[base + ln]      = (__bf16)(oacc[g][0][r] * inv);
            opart[base + 16 + ln] = (__bf16)(oacc[g][1][r] * inv);
        }
        if (quad == 0) {
            int qrow = qb + wave*32 + g*16 + ln;
            ml[((size_t)z*NH + head)*NN + qrow] = make_float2(m_[g], l_[g]);
        }
    }
}

// ---------------- combine split-K attention partials ----------------
__global__ __launch_bounds__(256) void attn_combine(const __bf16* __restrict__ opart,
        const float2* __restrict__ ml, float* __restrict__ o) {
    int row = blockIdx.x, c = threadIdx.x;
    int head = c >> 5;
    float2 t[SPLIT];
    float M = -1e30f;
    #pragma unroll
    for (int z = 0; z < SPLIT; z++) {
        t[z] = ml[((size_t)z*NH + head)*NN + row];
        M = fmaxf(M, t[z].x);
    }
    float acc = 0.f, wsum = 0.f;
    #pragma unroll
    for (int z = 0; z < SPLIT; z++) {
        float w = t[z].y * __builtin_amdgcn_exp2f(t[z].x - M);
        acc += w * (float)opart[((size_t)z*NN + row)*C + c];
        wsum += w;
    }
    o[(size_t)row*C + c] = acc / wsum;
}

extern "C" void kernel_launch(void* const* d_in, const int* in_sizes, int n_in,
                              void* d_out, int out_size, void* d_ws, size_t ws_size,
                              hipStream_t stream) {
    const float* x      = (const float*)d_in[0];
    const int*   ei     = (const int*)d_in[1];
    const float* lin1_w = (const float*)d_in[2];
    const float* lin1_b = (const float*)d_in[3];
    const float* gin_w1 = (const float*)d_in[4];
    const float* gin_b1 = (const float*)d_in[5];
    const float* gin_w2 = (const float*)d_in[6];
    const float* gin_b2 = (const float*)d_in[7];
    const float* wq = (const float*)d_in[8];
    const float* wk = (const float*)d_in[9];
    const float* wv = (const float*)d_in[10];
    const float* wo = (const float*)d_in[11];
    const float* bq = (const float*)d_in[12];
    const float* bk = (const float*)d_in[13];
    const float* bv = (const float*)d_in[14];
    const float* bo = (const float*)d_in[15];
    const float* bn1_g = (const float*)d_in[16];
    const float* bn1_b = (const float*)d_in[17];
    const float* bn2_g = (const float*)d_in[18];
    const float* bn2_b = (const float*)d_in[19];
    const float* bn3_g = (const float*)d_in[20];
    const float* bn3_b = (const float*)d_in[21];
    const float* mw1 = (const float*)d_in[22];
    const float* mb1 = (const float*)d_in[23];
    const float* mw2 = (const float*)d_in[24];
    const float* mb2 = (const float*)d_in[25];

    const size_t NC = (size_t)NN * C;
    float* bufA = (float*)d_ws;      // h (layer input)
    float* bufB = bufA + NC;         // agg; later ml partials; later gemm out
    float* bufC = bufB + NC;
    float* bufD = bufC + NC;
    float* bufE = bufD + NC;         // h1
    float* bufF = bufE + NC;         // attn o / h2
    float* bufG = bufF + NC;         // mlp hidden [NN,2C]; Opart during attn
    float* stats = bufG + 2*NC;      // 9 regions x 2C floats
    // bf16 QKV overlays bufC..bufD (free at qkv time)
    __bf16* Qb = (__bf16*)bufC;
    __bf16* Kb = Qb + NC;
    __bf16* Vb = Kb + NC;
    __bf16* Opart = (__bf16*)bufG;   // SPLIT*NN*C bf16 = 8 MB = bufG exactly
    float2* Oml = (float2*)bufB;     // SPLIT*NH*NN float2 = 1 MB

    dim3 blk(256);
    dim3 gemmCC(4, 64);
    dim3 gemmC2(8, 64);

    hipMemsetAsync(stats, 0, 9 * 2 * C * sizeof(float), stream);
    lin1_kernel<<<NN, blk, 0, stream>>>(x, lin1_w, lin1_b, bufA);

    for (int l = 0; l < NL; l++) {
        const float* gw1 = gin_w1 + (size_t)l*C*C;
        const float* gb1 = gin_b1 + (size_t)l*C;
        const float* gw2 = gin_w2 + (size_t)l*C*C;
        const float* gb2 = gin_b2 + (size_t)l*C;
        const float* lwq = wq + (size_t)l*C*C; const float* lbq = bq + (size_t)l*C;
        const float* lwk = wk + (size_t)l*C*C; const float* lbk = bk + (size_t)l*C;
        const float* lwv = wv + (size_t)l*C*C; const float* lbv = bv + (size_t)l*C;
        const float* lwo = wo + (size_t)l*C*C; const float* lbo = bo + (size_t)l*C;
        const float* lmw1 = mw1 + (size_t)l*2*C*C; const float* lmb1 = mb1 + (size_t)l*2*C;
        const float* lmw2 = mw2 + (size_t)l*2*C*C; const float* lmb2 = mb2 + (size_t)l*C;
        float* st1 = stats + (size_t)l*3*2*C;
        float* st2 = st1 + 2*C;
        float* st3 = st2 + 2*C;

        // ---- GIN branch ----
        hipMemsetAsync(bufB, 0, NC*sizeof(float), stream);
        scatter_kernel<<<NE, blk, 0, stream>>>(bufA, ei, bufB);
        gemm_bf16<<<gemmCC, blk, 0, stream>>>(bufA, bufB, gw1, gb1, nullptr, nullptr, bufC, nullptr, C, C, 1);
        gemm_bf16<<<gemmCC, blk, 0, stream>>>(bufC, nullptr, gw2, gb2, bufA, nullptr, bufD, st1, C, C, 0);
        bn_apply_kernel<<<NN, blk, 0, stream>>>(bufD, st1, bn1_g + (size_t)l*C, bn1_b + (size_t)l*C, bufE);

        // ---- attention branch (bufB free after gemm1; bufG free here) ----
        qkv_gemm<<<dim3(4, 64, 3), blk, 0, stream>>>(bufA, lwq, lwk, lwv, lbq, lbk, lbv, Qb, Kb, Vb);
        attn_kernel<<<dim3(NN/128, NH, SPLIT), blk, 0, stream>>>(Qb, Kb, Vb, Opart, Oml);
        attn_combine<<<NN, blk, 0, stream>>>(Opart, Oml, bufF);
        gemm_bf16<<<gemmCC, blk, 0, stream>>>(bufF, nullptr, lwo, lbo, bufA, nullptr, bufB, st2, C, C, 0);
        bn_apply_kernel<<<NN, blk, 0, stream>>>(bufB, st2, bn2_g + (size_t)l*C, bn2_b + (size_t)l*C, bufF);

        // ---- feedforward ----
        gemm_bf16<<<gemmC2, blk, 0, stream>>>(bufE, bufF, lmw1, lmb1, nullptr, nullptr, bufG, nullptr, C, 2*C, 1);
        gemm_bf16<<<gemmCC, blk, 0, stream>>>(bufG, nullptr, lmw2, lmb2, bufE, bufF, bufB, st3, 2*C, C, 0);
        float* hout = (l == NL-1) ? (float*)d_out : bufA;
        bn_apply_kernel<<<NN, blk, 0, stream>>>(bufB, st3, bn3_g + (size_t)l*C, bn3_b + (size_t)l*C, hout);
    }
}